// Round 1
// baseline (1343.702 us; speedup 1.0000x reference)
//
#include <hip/hip_runtime.h>

#define B_   8
#define CIN  3
#define H_   256
#define W_   256
#define QD   64
#define NCL  32
#define COUT 64
#define TS   16
#define TH   (TS + 2)   // 18: conv1-output tile with +1 halo
#define TX   (TS + 4)   // 20: x tile with +2 halo
#define SQP  1          // LDS pad
#define W1R_FLOATS (27 * 64)

// Repack weights for aligned float4, output-channel-contiguous access.
// w1: [64][3][9] (OIHW) -> w1r[(ci*9+k)*64 + c]
// w2: [64][64][9]       -> w2r[(c*9+k)*64 + o]
__global__ void repack_kernel(const float* __restrict__ w1, const float* __restrict__ w2,
                              float* __restrict__ w1r, float* __restrict__ w2r) {
    int t = blockIdx.x * blockDim.x + threadIdx.x;
    if (t < 64 * 3 * 9) {
        int c = t / 27, r = t % 27;           // r = ci*9+k
        w1r[r * 64 + c] = w1[t];
    }
    if (t < 64 * 64 * 9) {
        int o = t / 576, r = t % 576;         // r = c*9+k
        w2r[r * 64 + o] = w2[t];
    }
}

__global__ __launch_bounds__(256, 2) void fused_kernel(
    const float* __restrict__ x,
    const float* __restrict__ w1r, const float* __restrict__ b1,
    const float* __restrict__ w2r, const float* __restrict__ b2,
    const float* __restrict__ w3,  const float* __restrict__ b3,
    const float* __restrict__ mu,  const float* __restrict__ label,
    float* __restrict__ out)
{
    __shared__ float sx[CIN][TX][TX];             // 4800 B
    __shared__ float sq1[32][TH][TH + SQP];       // 43776 B (one 32-ch conv1 chunk)

    const int tid = threadIdx.x;
    const int w0 = blockIdx.x * TS;
    const int h0 = blockIdx.y * TS;
    const int b  = blockIdx.z;

    // ---- load x tile (rows/cols clamped = replicate padding) ----
    for (int i = tid; i < CIN * TX * TX; i += 256) {
        int ci = i / (TX * TX);
        int r  = (i / TX) % TX;
        int c  = i % TX;
        int gy = min(max(h0 - 2 + r, 0), H_ - 1);
        int gx = min(max(w0 - 2 + c, 0), W_ - 1);
        sx[ci][r][c] = x[((b * CIN + ci) * H_ + gy) * W_ + gx];
    }

    float acc[64];
#pragma unroll
    for (int o = 0; o < 64; ++o) acc[o] = b2[o];

    const int px = tid & 15;
    const int py = tid >> 4;

    for (int ch = 0; ch < 2; ++ch) {
        __syncthreads();   // sx ready (ch=0) / previous conv2 reads done (ch=1)

        // ---- conv1 (+ReLU) for channels [ch*32, ch*32+32) at 18x18 halo positions ----
        for (int pos = tid; pos < TH * TH; pos += 256) {
            int sy = pos / TH, sp = pos % TH;
            // image position this halo cell represents (replicate-clamped)
            int iy = min(max(h0 - 1 + sy, 0), H_ - 1);
            int ix = min(max(w0 - 1 + sp, 0), W_ - 1);
            // sx slot base so that sx[by+dy] == x[clamp(iy+dy-1)]
            int by = iy - (h0 - 1);
            int bx = ix - (w0 - 1);

            float xv[27];
#pragma unroll
            for (int ci = 0; ci < 3; ++ci)
#pragma unroll
                for (int dy = 0; dy < 3; ++dy)
#pragma unroll
                    for (int dx = 0; dx < 3; ++dx)
                        xv[ci * 9 + dy * 3 + dx] = sx[ci][by + dy][bx + dx];

            float a1[32];
#pragma unroll
            for (int c = 0; c < 32; ++c) a1[c] = b1[ch * 32 + c];
#pragma unroll
            for (int j = 0; j < 27; ++j) {
                const float4* wj = (const float4*)(w1r + j * 64 + ch * 32);
                float xj = xv[j];
#pragma unroll
                for (int c4 = 0; c4 < 8; ++c4) {
                    float4 wv = wj[c4];
                    a1[c4 * 4 + 0] += wv.x * xj;
                    a1[c4 * 4 + 1] += wv.y * xj;
                    a1[c4 * 4 + 2] += wv.z * xj;
                    a1[c4 * 4 + 3] += wv.w * xj;
                }
            }
#pragma unroll
            for (int c = 0; c < 32; ++c)
                sq1[c][sy][sp] = fmaxf(a1[c], 0.0f);
        }
        __syncthreads();   // sq1 ready

        // ---- conv2 accumulate over this 32-channel chunk ----
        for (int cl = 0; cl < 32; ++cl) {
            float v[9];
#pragma unroll
            for (int dy = 0; dy < 3; ++dy)
#pragma unroll
                for (int dx = 0; dx < 3; ++dx)
                    v[dy * 3 + dx] = sq1[cl][py + dy][px + dx];
            int c = ch * 32 + cl;
            const float4* wbase = (const float4*)(w2r + c * 576);
#pragma unroll
            for (int k = 0; k < 9; ++k) {
                float vk = v[k];
#pragma unroll
                for (int o4 = 0; o4 < 16; ++o4) {
                    float4 wv = wbase[k * 16 + o4];
                    acc[o4 * 4 + 0] += wv.x * vk;
                    acc[o4 * 4 + 1] += wv.y * vk;
                    acc[o4 * 4 + 2] += wv.z * vk;
                    acc[o4 * 4 + 3] += wv.w * vk;
                }
            }
        }
    }

    // ---- ReLU then 1x1 conv: q[o] = b3[o] + sum_c w3[o][c] * a[c] ----
#pragma unroll
    for (int o = 0; o < 64; ++o) acc[o] = fmaxf(acc[o], 0.0f);

    float q[64];
#pragma unroll
    for (int o = 0; o < 64; ++o) {
        const float4* wrow = (const float4*)(w3 + o * 64);
        float s = b3[o];
#pragma unroll
        for (int c4 = 0; c4 < 16; ++c4) {
            float4 wv = wrow[c4];
            s += wv.x * acc[c4 * 4 + 0] + wv.y * acc[c4 * 4 + 1]
               + wv.z * acc[c4 * 4 + 2] + wv.w * acc[c4 * 4 + 3];
        }
        q[o] = s;
    }

    // ---- logits = -(||q||^2 - 2 q.mu + ||mu||^2) over 32 clusters ----
    float qn = 0.f;
#pragma unroll
    for (int o = 0; o < 64; ++o) qn += q[o] * q[o];

    float lg[32];
#pragma unroll
    for (int n = 0; n < 32; ++n) {
        const float4* mrow = (const float4*)(mu + n * 64);
        float d = 0.f, m2 = 0.f;
#pragma unroll
        for (int c4 = 0; c4 < 16; ++c4) {
            float4 mv = mrow[c4];
            d  += mv.x * q[c4 * 4 + 0] + mv.y * q[c4 * 4 + 1]
                + mv.z * q[c4 * 4 + 2] + mv.w * q[c4 * 4 + 3];
            m2 += mv.x * mv.x + mv.y * mv.y + mv.z * mv.z + mv.w * mv.w;
        }
        lg[n] = 2.0f * d - m2 - qn;
    }

    // ---- softmax over 32 (in registers) ----
    float mx = lg[0];
#pragma unroll
    for (int n = 1; n < 32; ++n) mx = fmaxf(mx, lg[n]);
    float ssum = 0.f;
#pragma unroll
    for (int n = 0; n < 32; ++n) { lg[n] = __expf(lg[n] - mx); ssum += lg[n]; }
    float inv = 1.0f / ssum;

    // ---- out[o] = (sum_n label[o][n] * e[n]) / sum ----
    const int obase = (b * COUT * H_ + (h0 + py)) * W_ + (w0 + px);
#pragma unroll
    for (int o = 0; o < COUT; ++o) {
        const float4* lrow = (const float4*)(label + o * 32);
        float s = 0.f;
#pragma unroll
        for (int n4 = 0; n4 < 8; ++n4) {
            float4 lv = lrow[n4];
            s += lv.x * lg[n4 * 4 + 0] + lv.y * lg[n4 * 4 + 1]
               + lv.z * lg[n4 * 4 + 2] + lv.w * lg[n4 * 4 + 3];
        }
        out[obase + o * (H_ * W_)] = s * inv;
    }
}

extern "C" void kernel_launch(void* const* d_in, const int* in_sizes, int n_in,
                              void* d_out, int out_size, void* d_ws, size_t ws_size,
                              hipStream_t stream) {
    const float* x  = (const float*)d_in[0];
    const float* w1 = (const float*)d_in[1];
    const float* b1 = (const float*)d_in[2];
    const float* w2 = (const float*)d_in[3];
    const float* b2 = (const float*)d_in[4];
    const float* w3 = (const float*)d_in[5];
    const float* b3 = (const float*)d_in[6];
    const float* mu = (const float*)d_in[7];   // (1,32,64,1,1) -> [n*64+c]
    const float* lb = (const float*)d_in[8];   // (64,32)       -> [o*32+n]
    float* out = (float*)d_out;

    float* w1r = (float*)d_ws;                 // 27*64 floats
    float* w2r = w1r + W1R_FLOATS;             // 576*64 floats

    repack_kernel<<<(64 * 64 * 9 + 255) / 256, 256, 0, stream>>>(w1, w2, w1r, w2r);

    dim3 grid(W_ / TS, H_ / TS, B_);
    fused_kernel<<<grid, 256, 0, stream>>>(x, w1r, b1, w2r, b2, w3, b3, mu, lb, out);
}

// Round 2
// 222.778 us; speedup vs baseline: 6.0316x; 6.0316x over previous
//
#include <hip/hip_runtime.h>

typedef _Float16 f16x8 __attribute__((ext_vector_type(8)));
typedef float    f32x4 __attribute__((ext_vector_type(4)));

#define H_ 256
#define W_ 256

// workspace byte offsets (all 16B aligned)
#define WS_W1R   0        // 27*64 f32 = 6912
#define WS_W2S   6912     // 2 chunks * 9 taps * 64 rows * 64B fp16 = 73728
#define WS_STAGE 80640    // w3s(8192) + mus(4096) + labs(4096) + mun(128) = 16512
#define STAGE_U4 1032

// LDS byte offsets
#define L_SX   0          // 3*20*20 f32 = 4800
#define L_SQ1  4800       // 324 rows * 64B = 20736
#define L_W2S  25536      // 9*64*64B = 36864 (one chunk)
#define L_SQ2  4800       // 256 rows * 128B = 32768 (aliases SQ1+W2S, used after conv2)
#define L_PT   4800       // 256 rows * 64B = 16384 (aliases SQ2, used after q dead)
#define L_STG  62400      // 16512 staged consts
#define LDS_SZ 78912

__global__ void repack_kernel(const float* __restrict__ w1, const float* __restrict__ w2,
                              const float* __restrict__ w3, const float* __restrict__ mu,
                              const float* __restrict__ label, char* __restrict__ ws)
{
    int t = blockIdx.x * 256 + threadIdx.x;
    float*    w1r  = (float*)(ws + WS_W1R);
    _Float16* w2s  = (_Float16*)(ws + WS_W2S);
    _Float16* w3s  = (_Float16*)(ws + WS_STAGE);
    _Float16* mus  = (_Float16*)(ws + WS_STAGE + 8192);
    _Float16* labs = (_Float16*)(ws + WS_STAGE + 12288);
    float*    mun  = (float*)(ws + WS_STAGE + 16384);

    if (t < 1728) { int c = t / 27, r = t % 27; w1r[r * 64 + c] = w1[t]; }
    if (t < 36864) {           // w2[o][c][tap] -> per (chunk,tap): row n=o, 32 fp16, swizzled
        int n = t / 576, rem = t % 576, c = rem / 9, tap = rem % 9;
        int chunk = c >> 5, k = c & 31;
        int slot = (k >> 3) ^ ((n ^ (n >> 2)) & 3);
        w2s[((chunk * 9 + tap) * 64 + n) * 32 + slot * 8 + (k & 7)] = (_Float16)w2[t];
    }
    if (t < 4096) {            // w3[o][c] -> row o, 64 fp16, 3-bit swizzle
        int o = t >> 6, c = t & 63;
        int slot = (c >> 3) ^ (o & 7);
        w3s[o * 64 + slot * 8 + (c & 7)] = (_Float16)w3[t];
    }
    if (t < 2048) {            // mu[n][c] -> row n, 64 fp16 ; label[o][n] -> row o, 32 fp16
        int n = t >> 6, c = t & 63;
        int slot = (c >> 3) ^ (n & 7);
        mus[n * 64 + slot * 8 + (c & 7)] = (_Float16)mu[t];
        int o = t >> 5, cl = t & 31;
        int slot2 = (cl >> 3) ^ ((o ^ (o >> 2)) & 3);
        labs[o * 32 + slot2 * 8 + (cl & 7)] = (_Float16)label[t];
    }
    if (t < 32) { float s = 0.f; for (int c = 0; c < 64; ++c) { float v = mu[t * 64 + c]; s += v * v; } mun[t] = s; }
}

__global__ __launch_bounds__(256, 2) void fused_kernel(
    const float* __restrict__ x, const char* __restrict__ ws,
    const float* __restrict__ b1, const float* __restrict__ b2, const float* __restrict__ b3,
    float* __restrict__ out)
{
    __shared__ __align__(16) char smem[LDS_SZ];
    const int tid = threadIdx.x;
    const int lane = tid & 63;
    const int wv = tid >> 6;
    const int ln = lane & 15;
    const int lg = lane >> 4;
    const int swl = (ln ^ (ln >> 2)) & 3;   // 2-bit row swizzle for rows ≡ ln (mod 16)
    const int ln7 = ln & 7;

    const int w0 = blockIdx.x * 16, h0 = blockIdx.y * 16, bz = blockIdx.z;

    // ---- prefetch staged consts (linear copy, pre-swizzled in ws) ----
    {
        const uint4* s = (const uint4*)(ws + WS_STAGE);
        uint4* d = (uint4*)(smem + L_STG);
        for (int i = tid; i < STAGE_U4; i += 256) d[i] = s[i];
    }
    // ---- x tile (replicate clamp) ----
    {
        float* sx = (float*)(smem + L_SX);
        for (int i = tid; i < 1200; i += 256) {
            int ci = i / 400, r = (i / 20) % 20, c = i % 20;
            int gy = min(max(h0 - 2 + r, 0), H_ - 1);
            int gx = min(max(w0 - 2 + c, 0), W_ - 1);
            sx[i] = x[((bz * 3 + ci) * H_ + gy) * W_ + gx];
        }
    }
    // ---- stage conv2 weights chunk 0 ----
    {
        const uint4* s = (const uint4*)(ws + WS_W2S);
        uint4* d = (uint4*)(smem + L_W2S);
        for (int i = tid; i < 2304; i += 256) d[i] = s[i];
    }
    __syncthreads();

    f32x4 acc[4][4];
#pragma unroll
    for (int nb = 0; nb < 4; ++nb) {
        float bb = b2[nb * 16 + ln];
#pragma unroll
        for (int i = 0; i < 4; ++i) acc[i][nb] = (f32x4){bb, bb, bb, bb};
    }

    const float* w1r = (const float*)(ws + WS_W1R);
    const float* sx = (const float*)(smem + L_SX);

    for (int ch = 0; ch < 2; ++ch) {
        if (ch == 1) {   // stage chunk-1 weights (prev conv2 reads done at last barrier)
            const uint4* s = (const uint4*)(ws + WS_W2S + 36864);
            uint4* d = (uint4*)(smem + L_W2S);
            for (int i = tid; i < 2304; i += 256) d[i] = s[i];
        }
        // bias for this chunk
        float b1v[32];
#pragma unroll
        for (int c4 = 0; c4 < 8; ++c4) {
            float4 bv = *(const float4*)(b1 + ch * 32 + c4 * 4);
            b1v[c4 * 4 + 0] = bv.x; b1v[c4 * 4 + 1] = bv.y;
            b1v[c4 * 4 + 2] = bv.z; b1v[c4 * 4 + 3] = bv.w;
        }
        // ---- conv1 (+ReLU) for 32 channels at 18x18 halo positions, fp16 swizzled to sq1 ----
        for (int p = tid; p < 324; p += 256) {
            int sy = p / 18, sp = p % 18;
            int iy = min(max(h0 - 1 + sy, 0), H_ - 1);
            int ix = min(max(w0 - 1 + sp, 0), W_ - 1);
            int by = iy - (h0 - 1);
            int bx = ix - (w0 - 1);
            float xv[27];
#pragma unroll
            for (int ci = 0; ci < 3; ++ci)
#pragma unroll
                for (int dy = 0; dy < 3; ++dy)
#pragma unroll
                    for (int dx = 0; dx < 3; ++dx)
                        xv[ci * 9 + dy * 3 + dx] = sx[ci * 400 + (by + dy) * 20 + (bx + dx)];
            float a1[32];
#pragma unroll
            for (int c = 0; c < 32; ++c) a1[c] = b1v[c];
#pragma unroll
            for (int j = 0; j < 27; ++j) {
                const float4* wj = (const float4*)(w1r + j * 64 + ch * 32);
                float xj = xv[j];
#pragma unroll
                for (int c4 = 0; c4 < 8; ++c4) {
                    float4 wv = wj[c4];
                    a1[c4 * 4 + 0] += wv.x * xj; a1[c4 * 4 + 1] += wv.y * xj;
                    a1[c4 * 4 + 2] += wv.z * xj; a1[c4 * 4 + 3] += wv.w * xj;
                }
            }
            int swp = (p ^ (p >> 2)) & 3;
#pragma unroll
            for (int g = 0; g < 4; ++g) {
                union { _Float16 h[8]; uint4 u; } pk;
#pragma unroll
                for (int j = 0; j < 8; ++j) pk.h[j] = (_Float16)fmaxf(a1[g * 8 + j], 0.f);
                *(uint4*)(smem + L_SQ1 + p * 64 + ((g ^ swp) << 4)) = pk.u;
            }
        }
        __syncthreads();   // sq1 + w2s(chunk) ready

        // ---- conv2: 9 taps, K=32 per chunk, MFMA ----
#pragma unroll
        for (int tap = 0; tap < 9; ++tap) {
            const int dy = tap / 3, dx = tap % 3;
            f16x8 bf[4], af[4];
#pragma unroll
            for (int nb = 0; nb < 4; ++nb) {
                int n = nb * 16 + ln;
                bf[nb] = *(const f16x8*)(smem + L_W2S + ((tap * 64 + n) << 6) + ((lg ^ swl) << 4));
            }
#pragma unroll
            for (int i = 0; i < 4; ++i) {
                int pos = (wv * 4 + i + dy) * 18 + ln + dx;
                int swp = (pos ^ (pos >> 2)) & 3;
                af[i] = *(const f16x8*)(smem + L_SQ1 + (pos << 6) + ((lg ^ swp) << 4));
            }
#pragma unroll
            for (int i = 0; i < 4; ++i)
#pragma unroll
                for (int nb = 0; nb < 4; ++nb)
                    acc[i][nb] = __builtin_amdgcn_mfma_f32_16x16x32_f16(af[i], bf[nb], acc[i][nb], 0, 0, 0);
        }
        __syncthreads();   // conv2 reads done; sq1/w2s reusable
    }

    // ---- sq2 = fp16(relu(conv2)) , rows m x 64ch (128B rows, 3-bit swizzle) ----
#pragma unroll
    for (int i = 0; i < 4; ++i) {
        int mbase = (wv * 4 + i) * 16 + lg * 4;
#pragma unroll
        for (int nb = 0; nb < 4; ++nb) {
            int n = nb * 16 + ln, gg = n >> 3;
#pragma unroll
            for (int jr = 0; jr < 4; ++jr) {
                int m = mbase + jr;
                *(_Float16*)(smem + L_SQ2 + (m << 7) + ((gg ^ (m & 7)) << 4) + ((n & 7) << 1)) =
                    (_Float16)fmaxf(acc[i][nb][jr], 0.f);
            }
        }
    }
    __syncthreads();

    const char* w3s = smem + L_STG;
    const char* mus = smem + L_STG + 8192;
    const char* labs = smem + L_STG + 12288;
    const float* munp = (const float*)(smem + L_STG + 16384);

    // ---- 1x1 conv GEMM (K=64) ----
    f32x4 acc2[4][4];
#pragma unroll
    for (int nb = 0; nb < 4; ++nb) {
        float bb = b3[nb * 16 + ln];
#pragma unroll
        for (int i = 0; i < 4; ++i) acc2[i][nb] = (f32x4){bb, bb, bb, bb};
    }
#pragma unroll
    for (int ks = 0; ks < 2; ++ks) {
        const int sw3 = ((ks * 4 + lg) ^ ln7) << 4;
        f16x8 af[4], bf[4];
#pragma unroll
        for (int i = 0; i < 4; ++i) {
            int m = (wv * 4 + i) * 16 + ln;
            af[i] = *(const f16x8*)(smem + L_SQ2 + (m << 7) + sw3);
        }
#pragma unroll
        for (int nb = 0; nb < 4; ++nb) {
            int o = nb * 16 + ln;
            bf[nb] = *(const f16x8*)(w3s + (o << 7) + sw3);
        }
#pragma unroll
        for (int i = 0; i < 4; ++i)
#pragma unroll
            for (int nb = 0; nb < 4; ++nb)
                acc2[i][nb] = __builtin_amdgcn_mfma_f32_16x16x32_f16(af[i], bf[nb], acc2[i][nb], 0, 0, 0);
    }
    __syncthreads();   // 1x1 reads of sq2 done

    // ---- write q (fp16) back into sq2 layout ----
#pragma unroll
    for (int i = 0; i < 4; ++i) {
        int mbase = (wv * 4 + i) * 16 + lg * 4;
#pragma unroll
        for (int nb = 0; nb < 4; ++nb) {
            int n = nb * 16 + ln, gg = n >> 3;
#pragma unroll
            for (int jr = 0; jr < 4; ++jr) {
                int m = mbase + jr;
                *(_Float16*)(smem + L_SQ2 + (m << 7) + ((gg ^ (m & 7)) << 4) + ((n & 7) << 1)) =
                    (_Float16)acc2[i][nb][jr];
            }
        }
    }
    __syncthreads();

    // ---- distance GEMM: dot = q . mu  (N=32) ----
    f32x4 acc3[4][2];
#pragma unroll
    for (int i = 0; i < 4; ++i)
#pragma unroll
        for (int nb = 0; nb < 2; ++nb) acc3[i][nb] = (f32x4){0.f, 0.f, 0.f, 0.f};
#pragma unroll
    for (int ks = 0; ks < 2; ++ks) {
        const int sw3 = ((ks * 4 + lg) ^ ln7) << 4;
        f16x8 af[4], bf[2];
#pragma unroll
        for (int i = 0; i < 4; ++i) {
            int m = (wv * 4 + i) * 16 + ln;
            af[i] = *(const f16x8*)(smem + L_SQ2 + (m << 7) + sw3);
        }
#pragma unroll
        for (int nb = 0; nb < 2; ++nb) {
            int ncl = nb * 16 + ln;
            bf[nb] = *(const f16x8*)(mus + (ncl << 7) + sw3);
        }
#pragma unroll
        for (int i = 0; i < 4; ++i)
#pragma unroll
            for (int nb = 0; nb < 2; ++nb)
                acc3[i][nb] = __builtin_amdgcn_mfma_f32_16x16x32_f16(af[i], bf[nb], acc3[i][nb], 0, 0, 0);
    }

    // ---- softmax over 32 clusters (logit = 2*dot - ||mu||^2 ; ||q||^2 cancels) ----
    {
        float mun0 = munp[ln], mun1 = munp[16 + ln];
#pragma unroll
        for (int i = 0; i < 4; ++i)
#pragma unroll
            for (int jr = 0; jr < 4; ++jr) {
                float l0 = 2.f * acc3[i][0][jr] - mun0;
                float l1 = 2.f * acc3[i][1][jr] - mun1;
                float mx = fmaxf(l0, l1);
#pragma unroll
                for (int s = 1; s < 16; s <<= 1) mx = fmaxf(mx, __shfl_xor(mx, s));
                float e0 = __expf(l0 - mx), e1 = __expf(l1 - mx);
                float sm = e0 + e1;
#pragma unroll
                for (int s = 1; s < 16; s <<= 1) sm += __shfl_xor(sm, s);
                float inv = 1.f / sm;
                acc3[i][0][jr] = e0 * inv;
                acc3[i][1][jr] = e1 * inv;
            }
    }
    __syncthreads();   // distance reads of q done everywhere

    // ---- write attention p (fp16) to p-tile: rows m x 32 (64B rows, 2-bit swizzle) ----
#pragma unroll
    for (int i = 0; i < 4; ++i) {
        int mbase = (wv * 4 + i) * 16 + lg * 4;
#pragma unroll
        for (int nb = 0; nb < 2; ++nb) {
            int ncl = nb * 16 + ln, g = ncl >> 3;
#pragma unroll
            for (int jr = 0; jr < 4; ++jr) {
                int m = mbase + jr;
                int swp = (m ^ (m >> 2)) & 3;
                *(_Float16*)(smem + L_PT + (m << 6) + ((g ^ swp) << 4) + ((ncl & 7) << 1)) =
                    (_Float16)acc3[i][nb][jr];
            }
        }
    }
    __syncthreads();

    // ---- label GEMM (K=32) + store ----
    f32x4 acc4[4][4];
#pragma unroll
    for (int i = 0; i < 4; ++i)
#pragma unroll
        for (int nb = 0; nb < 4; ++nb) acc4[i][nb] = (f32x4){0.f, 0.f, 0.f, 0.f};
    {
        f16x8 af[4], bf[4];
#pragma unroll
        for (int i = 0; i < 4; ++i) {
            int m = (wv * 4 + i) * 16 + ln;
            af[i] = *(const f16x8*)(smem + L_PT + (m << 6) + ((lg ^ swl) << 4));
        }
#pragma unroll
        for (int nb = 0; nb < 4; ++nb) {
            int o = nb * 16 + ln;
            bf[nb] = *(const f16x8*)(labs + (o << 6) + ((lg ^ swl) << 4));
        }
#pragma unroll
        for (int i = 0; i < 4; ++i)
#pragma unroll
            for (int nb = 0; nb < 4; ++nb)
                acc4[i][nb] = __builtin_amdgcn_mfma_f32_16x16x32_f16(af[i], bf[nb], acc4[i][nb], 0, 0, 0);
    }
#pragma unroll
    for (int i = 0; i < 4; ++i) {
        int mb = wv * 4 + i;
#pragma unroll
        for (int nb = 0; nb < 4; ++nb) {
            int o = nb * 16 + ln;
#pragma unroll
            for (int jr = 0; jr < 4; ++jr) {
                int mx_ = lg * 4 + jr;
                out[((bz * 64 + o) * H_ + h0 + mb) * W_ + w0 + mx_] = acc4[i][nb][jr];
            }
        }
    }
}

extern "C" void kernel_launch(void* const* d_in, const int* in_sizes, int n_in,
                              void* d_out, int out_size, void* d_ws, size_t ws_size,
                              hipStream_t stream) {
    const float* x  = (const float*)d_in[0];
    const float* w1 = (const float*)d_in[1];
    const float* b1 = (const float*)d_in[2];
    const float* w2 = (const float*)d_in[3];
    const float* b2 = (const float*)d_in[4];
    const float* w3 = (const float*)d_in[5];
    const float* b3 = (const float*)d_in[6];
    const float* mu = (const float*)d_in[7];
    const float* lb = (const float*)d_in[8];
    float* out = (float*)d_out;
    char* ws = (char*)d_ws;

    repack_kernel<<<144, 256, 0, stream>>>(w1, w2, w3, mu, lb, ws);
    dim3 grid(W_ / 16, H_ / 16, 8);
    fused_kernel<<<grid, 256, 0, stream>>>(x, ws, b1, b2, b3, out);
}

// Round 4
// 82.629 us; speedup vs baseline: 16.2619x; 2.6961x over previous
//
#include <hip/hip_runtime.h>

typedef _Float16 f16x8 __attribute__((ext_vector_type(8)));
typedef __fp16   half2 __attribute__((ext_vector_type(2)));
typedef float    f32x4 __attribute__((ext_vector_type(4)));

#define H_ 256
#define W_ 256

// ws byte offsets
#define WS_W1S 0          // 64 rows x 32 f16 (k=ci*9+tap; k27=bias, 28..31=0) = 4096
#define WS_W2S 4096       // 2 chunks x 9 taps x 64 rows x 64B = 73728
#define WS_STG 77824      // Mws 4096 | labs 4096 | tn 128
#define STG_U4 520        // 8320 B

// LDS byte offsets
#define L_SX   0          // 1200 f32 = 4800
#define L_SQ1  4800       // 336 rows x 64B = 21504
#define L_W2S  26304      // 36864 (one chunk)
#define L_STG  63168      // 8320
#define L_SQ2  26304      // 256 rows x 128B = 32768 (aliases W2S after conv2)
#define L_PT   0          // 256 rows x 64B = 16384 (aliases SX+SQ1)
#define LDS_SZ 71488

__global__ void repack_kernel(const float* __restrict__ w1, const float* __restrict__ b1,
                              const float* __restrict__ w2, const float* __restrict__ w3,
                              const float* __restrict__ b3, const float* __restrict__ mu,
                              const float* __restrict__ label, char* __restrict__ ws)
{
    int t = blockIdx.x * 256 + threadIdx.x;
    _Float16* w1s  = (_Float16*)(ws + WS_W1S);
    _Float16* w2s  = (_Float16*)(ws + WS_W2S);
    _Float16* mws  = (_Float16*)(ws + WS_STG);
    _Float16* labs = (_Float16*)(ws + WS_STG + 4096);
    float*    tn   = (float*)(ws + WS_STG + 8192);

    if (t < 2048) {            // w1s rows n: k<27 -> w1, k==27 -> b1, else 0 (linear)
        int o = t >> 5, k = t & 31;
        float v = (k < 27) ? w1[o * 27 + k] : ((k == 27) ? b1[o] : 0.f);
        w1s[o * 32 + k] = (_Float16)v;
    }
    if (t < 36864) {           // w2[o][c][tap] -> [chunk][tap][row o][32 k], swizzled
        int n = t / 576, rem = t % 576, c = rem / 9, tap = rem % 9;
        int chunk = c >> 5, k = c & 31;
        int slot = (k >> 3) ^ ((n ^ (n >> 2)) & 3);
        w2s[((chunk * 9 + tap) * 64 + n) * 32 + slot * 8 + (k & 7)] = (_Float16)w2[t];
    }
    if (t < 2048) {            // Mw[n][c] = sum_o mu[n][o] w3[o][c], rows n x 64, swizzled
        int n = t >> 6, c = t & 63;
        float s = 0.f;
        for (int o = 0; o < 64; ++o) s += mu[n * 64 + o] * w3[o * 64 + c];
        int slot = (c >> 3) ^ (n & 7);
        mws[n * 64 + slot * 8 + (c & 7)] = (_Float16)s;
    }
    if (t < 2048) {            // label[o][n] rows o x 32, swizzled
        int o = t >> 5, cl = t & 31;
        int slot = (cl >> 3) ^ ((o ^ (o >> 2)) & 3);
        labs[o * 32 + slot * 8 + (cl & 7)] = (_Float16)label[o * 32 + cl];
    }
    if (t < 32) {              // tn = 2*mu.b3 - ||mu||^2
        float d = 0.f, m2 = 0.f;
        for (int o = 0; o < 64; ++o) { float m = mu[t * 64 + o]; d += m * b3[o]; m2 += m * m; }
        tn[t] = 2.f * d - m2;
    }
}

__global__ __launch_bounds__(256, 2) void fused_kernel(
    const float* __restrict__ x, const char* __restrict__ ws,
    const float* __restrict__ b2, float* __restrict__ out)
{
    __shared__ __align__(16) char smem[LDS_SZ];
    const int tid = threadIdx.x;
    const int lane = tid & 63;
    const int wv = tid >> 6;
    const int ln = lane & 15;
    const int lg = lane >> 4;
    const int swl = (ln ^ (ln >> 2)) & 3;
    const int w0 = blockIdx.x * 16, h0 = blockIdx.y * 16, bz = blockIdx.z;

    // ---- phase 0: stage consts + w2s chunk0 + x tile ----
    {
        const uint4* s = (const uint4*)(ws + WS_STG);
        uint4* d = (uint4*)(smem + L_STG);
        for (int i = tid; i < STG_U4; i += 256) d[i] = s[i];
    }
    {
        const uint4* s = (const uint4*)(ws + WS_W2S);
        uint4* d = (uint4*)(smem + L_W2S);
        for (int i = tid; i < 2304; i += 256) d[i] = s[i];
    }
    {
        float* sx = (float*)(smem + L_SX);
        for (int i = tid; i < 1200; i += 256) {
            int ci = i / 400, r = (i / 20) % 20, c = i % 20;
            int gy = min(max(h0 - 2 + r, 0), H_ - 1);
            int gx = min(max(w0 - 2 + c, 0), W_ - 1);
            sx[i] = x[((bz * 3 + ci) * H_ + gy) * W_ + gx];
        }
    }
    float b2v[4][4];
#pragma unroll
    for (int nb = 0; nb < 4; ++nb)
#pragma unroll
        for (int jr = 0; jr < 4; ++jr)
            b2v[nb][jr] = b2[nb * 16 + lg * 4 + jr];

    // conv1 im2col lane constants for k = lg*8+j
    int koff[8]; float kcv[8]; int kvalid[8];
#pragma unroll
    for (int j = 0; j < 8; ++j) {
        int k = lg * 8 + j;
        int ci = (k * 57) >> 9;          // k/9, valid k<27
        int r  = k - 9 * ci;
        int dy = (r * 22) >> 6;          // r/3
        int dx = r - 3 * dy;
        koff[j]   = ci * 400 + dy * 20 + dx;
        kvalid[j] = (k < 27);
        kcv[j]    = (k == 27) ? 1.0f : 0.0f;   // bias slot
    }

    __syncthreads();   // 1

    const f16x8* w1sp = (const f16x8*)(ws + WS_W1S);
    const float* sxp = (const float*)(smem + L_SX);

    f32x4 acc[4][4];
#pragma unroll
    for (int i = 0; i < 4; ++i)
#pragma unroll
        for (int nb = 0; nb < 4; ++nb)
            acc[i][nb] = (f32x4){b2v[nb][0], b2v[nb][1], b2v[nb][2], b2v[nb][3]};

    f16x8 bfr[6];
    int wrow[6], wswp[6];

    // ---- conv1 pass 0 (channels 0..31): build im2col frags + MFMA + packed writes ----
    {
        f16x8 w1f[2];
#pragma unroll
        for (int nb2 = 0; nb2 < 2; ++nb2)
            w1f[nb2] = w1sp[(nb2 * 16 + ln) * 4 + lg];
#pragma unroll
        for (int t = 0; t < 6; ++t) {
            int pb = wv + 4 * t;
            if (pb >= 21) break;
            int pos_w = pb * 16 + ln;
            int pos = min(pos_w, 323);
            int sy = (pos * 3641) >> 16;             // pos/18
            int sp = pos - sy * 18;
            int by = min(max(h0 - 1 + sy, 0), H_ - 1) - (h0 - 1);
            int bx = min(max(w0 - 1 + sp, 0), W_ - 1) - (w0 - 1);
            int base = by * 20 + bx;
            float g[8];
#pragma unroll
            for (int j = 0; j < 8; ++j) {
                float v = sxp[base + koff[j]];
                g[j] = kvalid[j] ? v : kcv[j];
            }
            union { half2 h2[4]; f16x8 f; } u;
#pragma unroll
            for (int jj = 0; jj < 4; ++jj)
                u.h2[jj] = __builtin_amdgcn_cvt_pkrtz(g[2 * jj], g[2 * jj + 1]);
            bfr[t] = u.f;
            wrow[t] = pos_w * 64 + ((lg & 1) << 3);
            wswp[t] = (pos_w ^ (pos_w >> 2)) & 3;
#pragma unroll
            for (int nb2 = 0; nb2 < 2; ++nb2) {
                f32x4 c0 = {0.f, 0.f, 0.f, 0.f};
                c0 = __builtin_amdgcn_mfma_f32_16x16x32_f16(w1f[nb2], bfr[t], c0, 0, 0, 0);
                union { half2 h2[2]; uint2 u2; } pk;
                pk.h2[0] = __builtin_amdgcn_cvt_pkrtz(fmaxf(c0[0], 0.f), fmaxf(c0[1], 0.f));
                pk.h2[1] = __builtin_amdgcn_cvt_pkrtz(fmaxf(c0[2], 0.f), fmaxf(c0[3], 0.f));
                int s2 = 2 * nb2 + (lg >> 1);
                *(uint2*)(smem + L_SQ1 + wrow[t] + ((s2 ^ wswp[t]) << 4)) = pk.u2;
            }
        }
    }
    __syncthreads();   // 2

    // ---- conv2 chunk 0 ----
#pragma unroll
    for (int tap = 0; tap < 9; ++tap) {
        const int dy = tap / 3, dx = tap % 3;
        f16x8 wf[4], qf[4];
#pragma unroll
        for (int nb = 0; nb < 4; ++nb)
            wf[nb] = *(const f16x8*)(smem + L_W2S + ((tap * 64 + nb * 16 + ln) << 6) + ((lg ^ swl) << 4));
#pragma unroll
        for (int i = 0; i < 4; ++i) {
            int pos = (wv * 4 + i + dy) * 18 + ln + dx;
            int sw = (pos ^ (pos >> 2)) & 3;
            qf[i] = *(const f16x8*)(smem + L_SQ1 + (pos << 6) + ((lg ^ sw) << 4));
        }
#pragma unroll
        for (int i = 0; i < 4; ++i)
#pragma unroll
            for (int nb = 0; nb < 4; ++nb)
                acc[i][nb] = __builtin_amdgcn_mfma_f32_16x16x32_f16(wf[nb], qf[i], acc[i][nb], 0, 0, 0);
    }
    __syncthreads();   // 3

    // ---- conv1 pass 1 (channels 32..63, reuse cached frags) + stage w2s chunk1 ----
    {
        const uint4* s = (const uint4*)(ws + WS_W2S + 36864);
        uint4* d = (uint4*)(smem + L_W2S);
        for (int i = tid; i < 2304; i += 256) d[i] = s[i];
    }
    {
        f16x8 w1f[2];
#pragma unroll
        for (int nb2 = 0; nb2 < 2; ++nb2)
            w1f[nb2] = w1sp[(32 + nb2 * 16 + ln) * 4 + lg];
#pragma unroll
        for (int t = 0; t < 6; ++t) {
            int pb = wv + 4 * t;
            if (pb >= 21) break;
#pragma unroll
            for (int nb2 = 0; nb2 < 2; ++nb2) {
                f32x4 c0 = {0.f, 0.f, 0.f, 0.f};
                c0 = __builtin_amdgcn_mfma_f32_16x16x32_f16(w1f[nb2], bfr[t], c0, 0, 0, 0);
                union { half2 h2[2]; uint2 u2; } pk;
                pk.h2[0] = __builtin_amdgcn_cvt_pkrtz(fmaxf(c0[0], 0.f), fmaxf(c0[1], 0.f));
                pk.h2[1] = __builtin_amdgcn_cvt_pkrtz(fmaxf(c0[2], 0.f), fmaxf(c0[3], 0.f));
                int s2 = 2 * nb2 + (lg >> 1);
                *(uint2*)(smem + L_SQ1 + wrow[t] + ((s2 ^ wswp[t]) << 4)) = pk.u2;
            }
        }
    }
    __syncthreads();   // 4

    // ---- conv2 chunk 1 ----
#pragma unroll
    for (int tap = 0; tap < 9; ++tap) {
        const int dy = tap / 3, dx = tap % 3;
        f16x8 wf[4], qf[4];
#pragma unroll
        for (int nb = 0; nb < 4; ++nb)
            wf[nb] = *(const f16x8*)(smem + L_W2S + ((tap * 64 + nb * 16 + ln) << 6) + ((lg ^ swl) << 4));
#pragma unroll
        for (int i = 0; i < 4; ++i) {
            int pos = (wv * 4 + i + dy) * 18 + ln + dx;
            int sw = (pos ^ (pos >> 2)) & 3;
            qf[i] = *(const f16x8*)(smem + L_SQ1 + (pos << 6) + ((lg ^ sw) << 4));
        }
#pragma unroll
        for (int i = 0; i < 4; ++i)
#pragma unroll
            for (int nb = 0; nb < 4; ++nb)
                acc[i][nb] = __builtin_amdgcn_mfma_f32_16x16x32_f16(wf[nb], qf[i], acc[i][nb], 0, 0, 0);
    }
    __syncthreads();   // 5

    // ---- a = relu(conv2) -> sq2 [pixel][64ch], b64 packed writes ----
#pragma unroll
    for (int i = 0; i < 4; ++i) {
        int pix = (wv * 4 + i) * 16 + ln;
        int sw = pix & 7;
#pragma unroll
        for (int nb = 0; nb < 4; ++nb) {
            union { half2 h2[2]; uint2 u2; } pk;
            pk.h2[0] = __builtin_amdgcn_cvt_pkrtz(fmaxf(acc[i][nb][0], 0.f), fmaxf(acc[i][nb][1], 0.f));
            pk.h2[1] = __builtin_amdgcn_cvt_pkrtz(fmaxf(acc[i][nb][2], 0.f), fmaxf(acc[i][nb][3], 0.f));
            int s2 = 2 * nb + (lg >> 1);
            *(uint2*)(smem + L_SQ2 + (pix << 7) + ((s2 ^ sw) << 4) + ((lg & 1) << 3)) = pk.u2;
        }
    }
    __syncthreads();   // 6

    // ---- distance GEMM: C[n][pixel] = Mw . a ; then in-lane softmax ----
    float tnr[8];
#pragma unroll
    for (int nb2 = 0; nb2 < 2; ++nb2)
#pragma unroll
        for (int jr = 0; jr < 4; ++jr)
            tnr[nb2 * 4 + jr] = *(const float*)(smem + L_STG + 8192 + ((nb2 * 16 + lg * 4 + jr) << 2));

    f32x4 acc3[4][2];
#pragma unroll
    for (int i = 0; i < 4; ++i)
#pragma unroll
        for (int nb2 = 0; nb2 < 2; ++nb2) acc3[i][nb2] = (f32x4){0.f, 0.f, 0.f, 0.f};
#pragma unroll
    for (int ks = 0; ks < 2; ++ks) {
        f16x8 mwf[2], af[4];
#pragma unroll
        for (int nb2 = 0; nb2 < 2; ++nb2)
            mwf[nb2] = *(const f16x8*)(smem + L_STG + ((nb2 * 16 + ln) << 7) + (((ks * 4 + lg) ^ (ln & 7)) << 4));
#pragma unroll
        for (int i = 0; i < 4; ++i) {
            int pix = (wv * 4 + i) * 16 + ln;
            af[i] = *(const f16x8*)(smem + L_SQ2 + (pix << 7) + (((ks * 4 + lg) ^ (pix & 7)) << 4));
        }
#pragma unroll
        for (int i = 0; i < 4; ++i)
#pragma unroll
            for (int nb2 = 0; nb2 < 2; ++nb2)
                acc3[i][nb2] = __builtin_amdgcn_mfma_f32_16x16x32_f16(mwf[nb2], af[i], acc3[i][nb2], 0, 0, 0);
    }

#pragma unroll
    for (int i = 0; i < 4; ++i) {
        float l[8];
#pragma unroll
        for (int nb2 = 0; nb2 < 2; ++nb2)
#pragma unroll
            for (int jr = 0; jr < 4; ++jr)
                l[nb2 * 4 + jr] = 2.f * acc3[i][nb2][jr] + tnr[nb2 * 4 + jr];
        float mx = l[0];
#pragma unroll
        for (int j = 1; j < 8; ++j) mx = fmaxf(mx, l[j]);
        mx = fmaxf(mx, __shfl_xor(mx, 16));
        mx = fmaxf(mx, __shfl_xor(mx, 32));
        float ssum = 0.f;
#pragma unroll
        for (int j = 0; j < 8; ++j) { l[j] = __expf(l[j] - mx); ssum += l[j]; }
        ssum += __shfl_xor(ssum, 16);
        ssum += __shfl_xor(ssum, 32);
        float inv = 1.f / ssum;
        int pix = (wv * 4 + i) * 16 + ln;
        int sw = (pix ^ (pix >> 2)) & 3;
#pragma unroll
        for (int nb2 = 0; nb2 < 2; ++nb2) {
            union { half2 h2[2]; uint2 u2; } pk;
            pk.h2[0] = __builtin_amdgcn_cvt_pkrtz(l[nb2 * 4 + 0] * inv, l[nb2 * 4 + 1] * inv);
            pk.h2[1] = __builtin_amdgcn_cvt_pkrtz(l[nb2 * 4 + 2] * inv, l[nb2 * 4 + 3] * inv);
            int s2 = 2 * nb2 + (lg >> 1);
            *(uint2*)(smem + L_PT + (pix << 6) + ((s2 ^ sw) << 4) + ((lg & 1) << 3)) = pk.u2;
        }
    }
    __syncthreads();   // 7

    // ---- label GEMM: C[o][pixel] = label . p ; coalesced stores ----
    f16x8 lf[4], pf[4];
#pragma unroll
    for (int nb = 0; nb < 4; ++nb)
        lf[nb] = *(const f16x8*)(smem + L_STG + 4096 + ((nb * 16 + ln) << 6) + ((lg ^ swl) << 4));
#pragma unroll
    for (int i = 0; i < 4; ++i) {
        int pix = (wv * 4 + i) * 16 + ln;
        int sw = (pix ^ (pix >> 2)) & 3;
        pf[i] = *(const f16x8*)(smem + L_PT + (pix << 6) + ((lg ^ sw) << 4));
    }
#pragma unroll
    for (int i = 0; i < 4; ++i) {
        int base = (bz * 64 * H_ + (h0 + wv * 4 + i)) * W_ + w0 + ln;
#pragma unroll
        for (int nb = 0; nb < 4; ++nb) {
            f32x4 c4 = {0.f, 0.f, 0.f, 0.f};
            c4 = __builtin_amdgcn_mfma_f32_16x16x32_f16(lf[nb], pf[i], c4, 0, 0, 0);
#pragma unroll
            for (int jr = 0; jr < 4; ++jr)
                out[base + (nb * 16 + lg * 4 + jr) * (H_ * W_)] = c4[jr];
        }
    }
}

extern "C" void kernel_launch(void* const* d_in, const int* in_sizes, int n_in,
                              void* d_out, int out_size, void* d_ws, size_t ws_size,
                              hipStream_t stream) {
    const float* x  = (const float*)d_in[0];
    const float* w1 = (const float*)d_in[1];
    const float* b1 = (const float*)d_in[2];
    const float* w2 = (const float*)d_in[3];
    const float* b2 = (const float*)d_in[4];
    const float* w3 = (const float*)d_in[5];
    const float* b3 = (const float*)d_in[6];
    const float* mu = (const float*)d_in[7];
    const float* lb = (const float*)d_in[8];
    float* out = (float*)d_out;
    char* ws = (char*)d_ws;

    repack_kernel<<<144, 256, 0, stream>>>(w1, b1, w2, w3, b3, mu, lb, ws);
    dim3 grid(W_ / 16, H_ / 16, 8);
    fused_kernel<<<grid, 256, 0, stream>>>(x, ws, b2, out);
}